// Round 13
// baseline (338.274 us; speedup 1.0000x reference)
//
#include <hip/hip_runtime.h>
#include <hip/hip_fp16.h>

#define N_NODES 100000
#define N_EDGES 3200000
#define HDIM 16
#define NB 391                 // buckets of 256 nodes
#define P1_BLOCKS 256
#define P1_THREADS 1024
#define P1_EPB 12500           // 256 * 12500 = 3.2M exactly
#define SLOT 64                // per (bucket, block) private slots: mean 32, sigma 5.7
#define BSTRIDE (P1_BLOCKS * SLOT)   // 16384 u32 per bucket region (also final col region)
#define SENT 0xFBFFFBFFu       // packed fp16 -65504 pair

typedef unsigned u32;
// native clang vector types (accepted by __builtin_nontemporal_*)
typedef float    vf4 __attribute__((ext_vector_type(4)));
typedef float    vf2 __attribute__((ext_vector_type(2)));
typedef unsigned vu4 __attribute__((ext_vector_type(4)));
typedef unsigned vu2 __attribute__((ext_vector_type(2)));
typedef int      vi2 __attribute__((ext_vector_type(2)));

__device__ __forceinline__ u32 pkmax(u32 a, u32 b) {
    u32 r;
    asm("v_pk_max_f16 %0, %1, %2" : "=v"(r) : "v"(a), "v"(b));
    return r;
}
__device__ __forceinline__ float2 h2f2(u32 u) {
    __half2 h = *reinterpret_cast<__half2*>(&u);
    return __half22float2(h);
}
__device__ __forceinline__ u32 f2h2(float a, float b) {
    __half2 h = __float22half2_rn(make_float2(a, b));
    return *reinterpret_cast<u32*>(&h);
}

// ---------------- pass1: single-pass bucket scatter into block-private regions ----------------
// Also folds fp32->fp16 conversion of x (2 vf4 per thread) + sentinel row.
// All global traffic here is streaming -> nontemporal (don't pollute L2).

__global__ __launch_bounds__(P1_THREADS)
void pass1_bucket(const int* __restrict__ src, const int* __restrict__ dst,
                  u32* __restrict__ priv, int* __restrict__ cnt,
                  const vf4* __restrict__ x, vu2* __restrict__ h0) {
    __shared__ int lh[NB];
    int t = threadIdx.x;
    int blk = blockIdx.x;

    // folded f2h: 256*1024*2 = 524288 >= 400000 float4s
    {
        int ci = blk * P1_THREADS + t;
        if (ci < N_NODES * HDIM / 4) {
            vf4 v = __builtin_nontemporal_load(&x[ci]);
            vu2 o; o.x = f2h2(v.x, v.y); o.y = f2h2(v.z, v.w);
            __builtin_nontemporal_store(o, &h0[ci]);
        }
        int ci2 = ci + P1_BLOCKS * P1_THREADS;
        if (ci2 < N_NODES * HDIM / 4) {
            vf4 v = __builtin_nontemporal_load(&x[ci2]);
            vu2 o; o.x = f2h2(v.x, v.y); o.y = f2h2(v.z, v.w);
            __builtin_nontemporal_store(o, &h0[ci2]);
        }
        if (blk == 0 && t < 8)
            ((u32*)h0)[(size_t)N_NODES * 8 + t] = SENT;   // sentinel row h0[N]
    }

    for (int i = t; i < NB; i += P1_THREADS) lh[i] = 0;
    __syncthreads();

    int e0 = blk * P1_EPB;
    int n = min(P1_EPB, N_EDGES - e0);
    for (int j = t; j < n; j += P1_THREADS) {
        int d = __builtin_nontemporal_load(&dst[e0 + j]);
        int s = __builtin_nontemporal_load(&src[e0 + j]);
        int bk = d >> 8;
        u32 pv = (u32)s | ((u32)(d & 255) << 17);
        int r = atomicAdd(&lh[bk], 1);
        if (r < SLOT)                              // statistically never false
            __builtin_nontemporal_store(pv, &priv[(size_t)bk * BSTRIDE + blk * SLOT + r]);
    }
    __syncthreads();
    for (int i = t; i < NB; i += P1_THREADS)
        cnt[i * P1_BLOCKS + blk] = min(lh[i], SLOT);
}

// ---------------- pass2: per-bucket counting sort -> row2 + padded col (in-place) ----------------

__global__ __launch_bounds__(1024)
void pass2_sort(u32* __restrict__ priv, const int* __restrict__ cnt,
                vi2* __restrict__ row2) {
    __shared__ int sdeg[256], spd[256], ssc[256], scnt[256];
    __shared__ int colst[13312];
    __shared__ int stot;
    int t = threadIdx.x;
    int b = blockIdx.x;
    size_t base = (size_t)b * BSTRIDE;
    int node0 = b << 8;
    int nn = min(256, N_NODES - node0);

    if (t < 256) { sdeg[t] = 0; scnt[t] = cnt[b * P1_BLOCKS + t]; }
    __syncthreads();

    u32 vv[16];
    int rr[16];
#pragma unroll
    for (int k = 0; k < 16; ++k) {                // 16*1024 = 16384 = 256 segs * 64 slots
        int idx = k * 1024 + t;
        int s = idx >> 6, sl = idx & 63;
        rr[k] = -1;
        if (sl < scnt[s]) {
            u32 v = __builtin_nontemporal_load(&priv[base + idx]);  // coalesced 256B runs
            vv[k] = v;
            rr[k] = atomicAdd(&sdeg[v >> 17], 1);
        }
    }
    __syncthreads();
    if (t < 256) {
        int d = sdeg[t];
        int pd = (d + 15) & ~15;                  // pad to multiple of 16 (0 stays 0)
        spd[t] = pd;
        ssc[t] = pd;
    }
    __syncthreads();
    for (int off = 1; off < 256; off <<= 1) {
        int u = 0;
        if (t < 256 && t >= off) u = ssc[t - off];
        __syncthreads();
        if (t < 256) ssc[t] += u;
        __syncthreads();
    }
    if (t < 256) {
        int ex = ssc[t] - spd[t];
        ssc[t] = ex;
        if (t < nn) {
            vi2 rv; rv.x = (int)base + ex; rv.y = (int)base + ex + spd[t];
            __builtin_nontemporal_store(rv, &row2[node0 + t]);
        }
        if (t == 255) stot = ex + spd[t];
        for (int q = ex + sdeg[t]; q < ex + spd[t]; ++q)
            colst[q] = N_NODES;                   // sentinel pad
    }
    __syncthreads();
#pragma unroll
    for (int k = 0; k < 16; ++k) {
        if (rr[k] >= 0)
            colst[ssc[vv[k] >> 17] + rr[k]] = vv[k] & 0x1FFFF;
    }
    __syncthreads();
    int tot = stot;                               // <= 13056; +48 guards <= 13104 < 16384
    for (int j = t; j < tot; j += 1024)
        __builtin_nontemporal_store((unsigned)colst[j], &priv[base + j]);
    if (t < 48)
        __builtin_nontemporal_store((unsigned)N_NODES, &priv[base + tot + t]);
}

// ---------------- fused SAGE layer: 8 lanes/node, feature-split, 2-deep pipelined gather ----------------
// Streaming traffic (col, row2, output) is nontemporal so L2 is reserved for the
// random h-row gathers (3.2MB table must stay resident in each XCD's 4MB L2).

template <int HOUT, bool RELU, bool LSM>
__global__ void sage_layer(const u32* __restrict__ h,       // fp16 rows: 8 u32/node, N+1 rows
                           const vi2* __restrict__ row2,
                           const unsigned* __restrict__ col,
                           const float* __restrict__ Wl,
                           const float* __restrict__ Wr,
                           const float* __restrict__ b,
                           void* __restrict__ out) {
    __shared__ float sWl[HDIM * HOUT];
    __shared__ float sWr[HDIM * HOUT];
    __shared__ float sb[HOUT];
    int t = threadIdx.x;
    if (t < HDIM * HOUT) { sWl[t] = Wl[t]; sWr[t] = Wr[t]; }
    if (t < HOUT) sb[t] = b[t];
    if (HOUT == 16) {
        if (blockIdx.x == 0 && t < 8)
            ((u32*)out)[(size_t)N_NODES * 8 + t] = SENT;   // sentinel row for next layer
    }
    // no __syncthreads here — gather loop doesn't touch LDS; sync before matmul

    int nl = t >> 3, g = t & 7, p = g >> 1, hf = g & 1;
    int i = blockIdx.x * 32 + nl;                 // grid covers N exactly (3125*32)

    vi2 r2 = __builtin_nontemporal_load(&row2[i]);
    int beg = r2.x, endp = r2.y;
    const uint4* h4 = (const uint4*)h;
    const unsigned* cp = col + 4 * p;

    uint4 xr = h4[i * 2 + hf];

    // prologue: cols for iter0 and iter1, gathers for iter0
    vu4 cc = __builtin_nontemporal_load((const vu4*)(cp + beg));
    vu4 nc = __builtin_nontemporal_load((const vu4*)(cp + beg + 16));
    uint4 v0 = h4[(int)cc.x * 2 + hf];
    uint4 v1 = h4[(int)cc.y * 2 + hf];
    uint4 v2 = h4[(int)cc.z * 2 + hf];
    uint4 v3 = h4[(int)cc.w * 2 + hf];

    u32 a0 = SENT, a1 = SENT, a2 = SENT, a3 = SENT;
    for (int j = beg; j < endp; j += 16) {
        // issue iter k+1 gathers and iter k+2 cols (sentinel-guarded)
        uint4 w0 = h4[(int)nc.x * 2 + hf];
        uint4 w1 = h4[(int)nc.y * 2 + hf];
        uint4 w2 = h4[(int)nc.z * 2 + hf];
        uint4 w3 = h4[(int)nc.w * 2 + hf];
        vu4 nc2 = __builtin_nontemporal_load((const vu4*)(cp + j + 32));
        // consume iter k
        a0 = pkmax(a0, pkmax(pkmax(v0.x, v1.x), pkmax(v2.x, v3.x)));
        a1 = pkmax(a1, pkmax(pkmax(v0.y, v1.y), pkmax(v2.y, v3.y)));
        a2 = pkmax(a2, pkmax(pkmax(v0.z, v1.z), pkmax(v2.z, v3.z)));
        a3 = pkmax(a3, pkmax(pkmax(v0.w, v1.w), pkmax(v2.w, v3.w)));
        v0 = w0; v1 = w1; v2 = w2; v3 = w3;
        nc = nc2;
    }
    // combine the 4 lane-pairs (same half hf)
#pragma unroll
    for (int m = 2; m <= 4; m <<= 1) {
        a0 = pkmax(a0, (u32)__shfl_xor((int)a0, m));
        a1 = pkmax(a1, (u32)__shfl_xor((int)a1, m));
        a2 = pkmax(a2, (u32)__shfl_xor((int)a2, m));
        a3 = pkmax(a3, (u32)__shfl_xor((int)a3, m));
    }
    if (beg == endp) { a0 = a1 = a2 = a3 = 0u; }  // isolated node -> 0

    float fa[8], fx[8];
    {
        float2 f;
        f = h2f2(a0);   fa[0] = f.x; fa[1] = f.y;
        f = h2f2(a1);   fa[2] = f.x; fa[3] = f.y;
        f = h2f2(a2);   fa[4] = f.x; fa[5] = f.y;
        f = h2f2(a3);   fa[6] = f.x; fa[7] = f.y;
        f = h2f2(xr.x); fx[0] = f.x; fx[1] = f.y;
        f = h2f2(xr.y); fx[2] = f.x; fx[3] = f.y;
        f = h2f2(xr.z); fx[4] = f.x; fx[5] = f.y;
        f = h2f2(xr.w); fx[6] = f.x; fx[7] = f.y;
    }
    int fb = hf * 8;

    __syncthreads();                              // weights now needed

    if (HOUT == 16) {
        float o0 = 0.f, o1 = 0.f, o2 = 0.f, o3 = 0.f;
#pragma unroll
        for (int q = 0; q < 8; ++q) {
            int f = fb + q;
            float4 wl = ((const float4*)sWl)[f * 4 + p];
            float4 wr = ((const float4*)sWr)[f * 4 + p];
            o0 += fa[q] * wl.x + fx[q] * wr.x;
            o1 += fa[q] * wl.y + fx[q] * wr.y;
            o2 += fa[q] * wl.z + fx[q] * wr.z;
            o3 += fa[q] * wl.w + fx[q] * wr.w;
        }
        o0 += __shfl_xor(o0, 1);
        o1 += __shfl_xor(o1, 1);
        o2 += __shfl_xor(o2, 1);
        o3 += __shfl_xor(o3, 1);
        if (hf == 0) {
            int c0 = p * 4;
            o0 += sb[c0]; o1 += sb[c0 + 1]; o2 += sb[c0 + 2]; o3 += sb[c0 + 3];
            if (RELU) {
                o0 = fmaxf(o0, 0.f); o1 = fmaxf(o1, 0.f);
                o2 = fmaxf(o2, 0.f); o3 = fmaxf(o3, 0.f);
            }
            vu2 ov; ov.x = f2h2(o0, o1); ov.y = f2h2(o2, o3);
            __builtin_nontemporal_store(ov, &((vu2*)out)[i * 4 + p]);
        }
    } else {  // HOUT == 2 final layer, fp32 out + log_softmax
        float o0 = 0.f, o1 = 0.f;
#pragma unroll
        for (int q = 0; q < 8; ++q) {
            int f = fb + q;
            o0 += fa[q] * sWl[f * 2 + 0] + fx[q] * sWr[f * 2 + 0];
            o1 += fa[q] * sWl[f * 2 + 1] + fx[q] * sWr[f * 2 + 1];
        }
        o0 += __shfl_xor(o0, 1);
        o1 += __shfl_xor(o1, 1);
        if (g == 0) {
            o0 += sb[0]; o1 += sb[1];
            if (LSM) {
                float m = fmaxf(o0, o1);
                float lse = m + logf(expf(o0 - m) + expf(o1 - m));
                o0 -= lse; o1 -= lse;
            }
            vf2 ov; ov.x = o0; ov.y = o1;
            __builtin_nontemporal_store(ov, &((vf2*)out)[i]);
        }
    }
}

// ---------------- launch ----------------

extern "C" void kernel_launch(void* const* d_in, const int* in_sizes, int n_in,
                              void* d_out, int out_size, void* d_ws, size_t ws_size,
                              hipStream_t stream) {
    const float* x      = (const float*)d_in[0];
    const int*   ei     = (const int*)d_in[1];
    const float* Wl1    = (const float*)d_in[2];
    const float* Wr1    = (const float*)d_in[3];
    const float* b1     = (const float*)d_in[4];
    const float* Wl_mid = (const float*)d_in[5];
    const float* Wr_mid = (const float*)d_in[6];
    const float* b_mid  = (const float*)d_in[7];
    const float* Wl7    = (const float*)d_in[8];
    const float* Wr7    = (const float*)d_in[9];
    const float* b7     = (const float*)d_in[10];
    float* out = (float*)d_out;

    const int* src = ei;
    const int* dst = ei + N_EDGES;

    char* ws = (char*)d_ws;
    size_t off = 0;
    auto alloc = [&](size_t bytes) {
        void* p = ws + off;
        off += (bytes + 255) & ~(size_t)255;
        return p;
    };
    u32*  priv = (u32*)alloc((size_t)NB * BSTRIDE * 4);   // pass1 pairs -> final padded col
    int*  cnt  = (int*)alloc((size_t)NB * P1_BLOCKS * 4);
    vi2*  row2 = (vi2*)alloc((size_t)N_NODES * 8);
    u32*  h0   = (u32*)alloc((size_t)(N_NODES + 1) * HDIM * 2);  // fp16, +sentinel row
    u32*  hA   = (u32*)alloc((size_t)(N_NODES + 1) * HDIM * 2);
    u32*  hB   = (u32*)alloc((size_t)(N_NODES + 1) * HDIM * 2);

    dim3 bL((N_NODES + 31) / 32);   // 3125 blocks x 256 threads (8 lanes/node)

    // ---- CSR build (pass1 also converts x -> fp16 h0) ----
    pass1_bucket<<<P1_BLOCKS, P1_THREADS, 0, stream>>>(src, dst, priv, cnt,
                                                       (const vf4*)x, (vu2*)h0);
    pass2_sort<<<NB, 1024, 0, stream>>>(priv, cnt, row2);

    // ---- 7 fused layers ----
    sage_layer<16, true, false><<<bL, 256, 0, stream>>>(h0, row2, priv, Wl1, Wr1, b1, hA);

    u32* cur = hA;
    u32* nxt = hB;
    for (int i = 0; i < 5; ++i) {
        sage_layer<16, true, false><<<bL, 256, 0, stream>>>(
            cur, row2, priv, Wl_mid + i * 256, Wr_mid + i * 256, b_mid + i * 16, nxt);
        u32* tmp = cur; cur = nxt; nxt = tmp;
    }

    sage_layer<2, false, true><<<bL, 256, 0, stream>>>(cur, row2, priv, Wl7, Wr7, b7, out);
}

// Round 14
// 247.326 us; speedup vs baseline: 1.3677x; 1.3677x over previous
//
#include <hip/hip_runtime.h>
#include <hip/hip_fp16.h>

#define N_NODES 100000
#define N_EDGES 3200000
#define HDIM 16
#define NB 391                 // buckets of 256 nodes
#define P1_BLOCKS 256
#define P1_THREADS 1024
#define P1_EPB 12500           // 256 * 12500 = 3.2M exactly
#define SLOT 64                // per (bucket, block) private slots: mean 32, sigma 5.7
#define BSTRIDE (P1_BLOCKS * SLOT)   // 16384 u32 per bucket region (also final col region)
#define SENT 0xFBFFFBFFu       // packed fp16 -65504 pair

typedef unsigned u32;
// native clang vector types (accepted by __builtin_nontemporal_*)
typedef unsigned vu4 __attribute__((ext_vector_type(4)));
typedef int      vi2 __attribute__((ext_vector_type(2)));

__device__ __forceinline__ u32 pkmax(u32 a, u32 b) {
    u32 r;
    asm("v_pk_max_f16 %0, %1, %2" : "=v"(r) : "v"(a), "v"(b));
    return r;
}
__device__ __forceinline__ float2 h2f2(u32 u) {
    __half2 h = *reinterpret_cast<__half2*>(&u);
    return __half22float2(h);
}
__device__ __forceinline__ u32 f2h2(float a, float b) {
    __half2 h = __float22half2_rn(make_float2(a, b));
    return *reinterpret_cast<u32*>(&h);
}

// ---------------- pass1: single-pass bucket scatter into block-private regions ----------------
// Also folds fp32->fp16 conversion of x (2 float4 per thread) + sentinel row.
// (All cached accesses — NT stores on scattered writes caused 8x write amplification, r13.)

__global__ __launch_bounds__(P1_THREADS)
void pass1_bucket(const int* __restrict__ src, const int* __restrict__ dst,
                  u32* __restrict__ priv, int* __restrict__ cnt,
                  const float4* __restrict__ x, uint2* __restrict__ h0) {
    __shared__ int lh[NB];
    int t = threadIdx.x;
    int blk = blockIdx.x;

    // folded f2h: 256*1024*2 = 524288 >= 400000 float4s
    {
        int ci = blk * P1_THREADS + t;
        if (ci < N_NODES * HDIM / 4) {
            float4 v = x[ci];
            h0[ci] = make_uint2(f2h2(v.x, v.y), f2h2(v.z, v.w));
        }
        int ci2 = ci + P1_BLOCKS * P1_THREADS;
        if (ci2 < N_NODES * HDIM / 4) {
            float4 v = x[ci2];
            h0[ci2] = make_uint2(f2h2(v.x, v.y), f2h2(v.z, v.w));
        }
        if (blk == 0 && t < 8)
            ((u32*)h0)[(size_t)N_NODES * 8 + t] = SENT;   // sentinel row h0[N]
    }

    for (int i = t; i < NB; i += P1_THREADS) lh[i] = 0;
    __syncthreads();

    int e0 = blk * P1_EPB;
    int n = min(P1_EPB, N_EDGES - e0);
    for (int j = t; j < n; j += P1_THREADS) {
        int d = dst[e0 + j];
        int s = src[e0 + j];
        int bk = d >> 8;
        u32 pv = (u32)s | ((u32)(d & 255) << 17);
        int r = atomicAdd(&lh[bk], 1);
        if (r < SLOT)                              // statistically never false
            priv[(size_t)bk * BSTRIDE + blk * SLOT + r] = pv;
    }
    __syncthreads();
    for (int i = t; i < NB; i += P1_THREADS)
        cnt[i * P1_BLOCKS + blk] = min(lh[i], SLOT);
}

// ---------------- pass2: per-bucket counting sort -> row2 + padded col (in-place) ----------------

__global__ __launch_bounds__(1024)
void pass2_sort(u32* __restrict__ priv, const int* __restrict__ cnt,
                int2* __restrict__ row2) {
    __shared__ int sdeg[256], spd[256], ssc[256], scnt[256];
    __shared__ int colst[13312];
    __shared__ int stot;
    int t = threadIdx.x;
    int b = blockIdx.x;
    size_t base = (size_t)b * BSTRIDE;
    int node0 = b << 8;
    int nn = min(256, N_NODES - node0);

    if (t < 256) { sdeg[t] = 0; scnt[t] = cnt[b * P1_BLOCKS + t]; }
    __syncthreads();

    u32 vv[16];
    int rr[16];
#pragma unroll
    for (int k = 0; k < 16; ++k) {                // 16*1024 = 16384 = 256 segs * 64 slots
        int idx = k * 1024 + t;
        int s = idx >> 6, sl = idx & 63;
        rr[k] = -1;
        if (sl < scnt[s]) {
            u32 v = priv[base + idx];             // seg-major: coalesced 256B runs
            vv[k] = v;
            rr[k] = atomicAdd(&sdeg[v >> 17], 1);
        }
    }
    __syncthreads();
    if (t < 256) {
        int d = sdeg[t];
        int pd = (d + 15) & ~15;                  // pad to multiple of 16 (0 stays 0)
        spd[t] = pd;
        ssc[t] = pd;
    }
    __syncthreads();
    for (int off = 1; off < 256; off <<= 1) {
        int u = 0;
        if (t < 256 && t >= off) u = ssc[t - off];
        __syncthreads();
        if (t < 256) ssc[t] += u;
        __syncthreads();
    }
    if (t < 256) {
        int ex = ssc[t] - spd[t];
        ssc[t] = ex;
        if (t < nn) row2[node0 + t] = make_int2((int)base + ex, (int)base + ex + spd[t]);
        if (t == 255) stot = ex + spd[t];
        for (int q = ex + sdeg[t]; q < ex + spd[t]; ++q)
            colst[q] = N_NODES;                   // sentinel pad
    }
    __syncthreads();
#pragma unroll
    for (int k = 0; k < 16; ++k) {
        if (rr[k] >= 0)
            colst[ssc[vv[k] >> 17] + rr[k]] = vv[k] & 0x1FFFF;
    }
    __syncthreads();
    int tot = stot;                               // <= 13056; +48 guards <= 13104 < 16384
    for (int j = t; j < tot; j += 1024) priv[base + j] = (unsigned)colst[j];
    if (t < 48) priv[base + tot + t] = N_NODES;   // prefetch guard sentinels
}

// ---------------- fused SAGE layer: 8 lanes/node, feature-split, 2-deep pipelined gather ----------------
// NT applied ONLY to coalesced read-once streaming loads (col, row2) so those lines
// don't evict the 3.2MB h gather table from each XCD's 4MB L2. All stores cached.

template <int HOUT, bool RELU, bool LSM>
__global__ void sage_layer(const u32* __restrict__ h,       // fp16 rows: 8 u32/node, N+1 rows
                           const vi2* __restrict__ row2,
                           const unsigned* __restrict__ col,
                           const float* __restrict__ Wl,
                           const float* __restrict__ Wr,
                           const float* __restrict__ b,
                           void* __restrict__ out) {
    __shared__ float sWl[HDIM * HOUT];
    __shared__ float sWr[HDIM * HOUT];
    __shared__ float sb[HOUT];
    int t = threadIdx.x;
    if (t < HDIM * HOUT) { sWl[t] = Wl[t]; sWr[t] = Wr[t]; }
    if (t < HOUT) sb[t] = b[t];
    if (HOUT == 16) {
        if (blockIdx.x == 0 && t < 8)
            ((u32*)out)[(size_t)N_NODES * 8 + t] = SENT;   // sentinel row for next layer
    }
    // no __syncthreads here — gather loop doesn't touch LDS; sync before matmul

    int nl = t >> 3, g = t & 7, p = g >> 1, hf = g & 1;
    int i = blockIdx.x * 32 + nl;                 // grid covers N exactly (3125*32)

    vi2 r2 = __builtin_nontemporal_load(&row2[i]);
    int beg = r2.x, endp = r2.y;
    const uint4* h4 = (const uint4*)h;
    const unsigned* cp = col + 4 * p;

    uint4 xr = h4[i * 2 + hf];

    // prologue: cols for iter0 and iter1, gathers for iter0
    vu4 cc = __builtin_nontemporal_load((const vu4*)(cp + beg));
    vu4 nc = __builtin_nontemporal_load((const vu4*)(cp + beg + 16));
    uint4 v0 = h4[(int)cc.x * 2 + hf];
    uint4 v1 = h4[(int)cc.y * 2 + hf];
    uint4 v2 = h4[(int)cc.z * 2 + hf];
    uint4 v3 = h4[(int)cc.w * 2 + hf];

    u32 a0 = SENT, a1 = SENT, a2 = SENT, a3 = SENT;
    for (int j = beg; j < endp; j += 16) {
        // issue iter k+1 gathers and iter k+2 cols (sentinel-guarded)
        uint4 w0 = h4[(int)nc.x * 2 + hf];
        uint4 w1 = h4[(int)nc.y * 2 + hf];
        uint4 w2 = h4[(int)nc.z * 2 + hf];
        uint4 w3 = h4[(int)nc.w * 2 + hf];
        vu4 nc2 = __builtin_nontemporal_load((const vu4*)(cp + j + 32));
        // consume iter k
        a0 = pkmax(a0, pkmax(pkmax(v0.x, v1.x), pkmax(v2.x, v3.x)));
        a1 = pkmax(a1, pkmax(pkmax(v0.y, v1.y), pkmax(v2.y, v3.y)));
        a2 = pkmax(a2, pkmax(pkmax(v0.z, v1.z), pkmax(v2.z, v3.z)));
        a3 = pkmax(a3, pkmax(pkmax(v0.w, v1.w), pkmax(v2.w, v3.w)));
        v0 = w0; v1 = w1; v2 = w2; v3 = w3;
        nc = nc2;
    }
    // combine the 4 lane-pairs (same half hf)
#pragma unroll
    for (int m = 2; m <= 4; m <<= 1) {
        a0 = pkmax(a0, (u32)__shfl_xor((int)a0, m));
        a1 = pkmax(a1, (u32)__shfl_xor((int)a1, m));
        a2 = pkmax(a2, (u32)__shfl_xor((int)a2, m));
        a3 = pkmax(a3, (u32)__shfl_xor((int)a3, m));
    }
    if (beg == endp) { a0 = a1 = a2 = a3 = 0u; }  // isolated node -> 0

    float fa[8], fx[8];
    {
        float2 f;
        f = h2f2(a0);   fa[0] = f.x; fa[1] = f.y;
        f = h2f2(a1);   fa[2] = f.x; fa[3] = f.y;
        f = h2f2(a2);   fa[4] = f.x; fa[5] = f.y;
        f = h2f2(a3);   fa[6] = f.x; fa[7] = f.y;
        f = h2f2(xr.x); fx[0] = f.x; fx[1] = f.y;
        f = h2f2(xr.y); fx[2] = f.x; fx[3] = f.y;
        f = h2f2(xr.z); fx[4] = f.x; fx[5] = f.y;
        f = h2f2(xr.w); fx[6] = f.x; fx[7] = f.y;
    }
    int fb = hf * 8;

    __syncthreads();                              // weights now needed

    if (HOUT == 16) {
        float o0 = 0.f, o1 = 0.f, o2 = 0.f, o3 = 0.f;
#pragma unroll
        for (int q = 0; q < 8; ++q) {
            int f = fb + q;
            float4 wl = ((const float4*)sWl)[f * 4 + p];
            float4 wr = ((const float4*)sWr)[f * 4 + p];
            o0 += fa[q] * wl.x + fx[q] * wr.x;
            o1 += fa[q] * wl.y + fx[q] * wr.y;
            o2 += fa[q] * wl.z + fx[q] * wr.z;
            o3 += fa[q] * wl.w + fx[q] * wr.w;
        }
        o0 += __shfl_xor(o0, 1);
        o1 += __shfl_xor(o1, 1);
        o2 += __shfl_xor(o2, 1);
        o3 += __shfl_xor(o3, 1);
        if (hf == 0) {
            int c0 = p * 4;
            o0 += sb[c0]; o1 += sb[c0 + 1]; o2 += sb[c0 + 2]; o3 += sb[c0 + 3];
            if (RELU) {
                o0 = fmaxf(o0, 0.f); o1 = fmaxf(o1, 0.f);
                o2 = fmaxf(o2, 0.f); o3 = fmaxf(o3, 0.f);
            }
            ((uint2*)out)[i * 4 + p] = make_uint2(f2h2(o0, o1), f2h2(o2, o3));
        }
    } else {  // HOUT == 2 final layer, fp32 out + log_softmax
        float o0 = 0.f, o1 = 0.f;
#pragma unroll
        for (int q = 0; q < 8; ++q) {
            int f = fb + q;
            o0 += fa[q] * sWl[f * 2 + 0] + fx[q] * sWr[f * 2 + 0];
            o1 += fa[q] * sWl[f * 2 + 1] + fx[q] * sWr[f * 2 + 1];
        }
        o0 += __shfl_xor(o0, 1);
        o1 += __shfl_xor(o1, 1);
        if (g == 0) {
            o0 += sb[0]; o1 += sb[1];
            if (LSM) {
                float m = fmaxf(o0, o1);
                float lse = m + logf(expf(o0 - m) + expf(o1 - m));
                o0 -= lse; o1 -= lse;
            }
            ((float2*)out)[i] = make_float2(o0, o1);
        }
    }
}

// ---------------- launch ----------------

extern "C" void kernel_launch(void* const* d_in, const int* in_sizes, int n_in,
                              void* d_out, int out_size, void* d_ws, size_t ws_size,
                              hipStream_t stream) {
    const float* x      = (const float*)d_in[0];
    const int*   ei     = (const int*)d_in[1];
    const float* Wl1    = (const float*)d_in[2];
    const float* Wr1    = (const float*)d_in[3];
    const float* b1     = (const float*)d_in[4];
    const float* Wl_mid = (const float*)d_in[5];
    const float* Wr_mid = (const float*)d_in[6];
    const float* b_mid  = (const float*)d_in[7];
    const float* Wl7    = (const float*)d_in[8];
    const float* Wr7    = (const float*)d_in[9];
    const float* b7     = (const float*)d_in[10];
    float* out = (float*)d_out;

    const int* src = ei;
    const int* dst = ei + N_EDGES;

    char* ws = (char*)d_ws;
    size_t off = 0;
    auto alloc = [&](size_t bytes) {
        void* p = ws + off;
        off += (bytes + 255) & ~(size_t)255;
        return p;
    };
    u32*  priv = (u32*)alloc((size_t)NB * BSTRIDE * 4);   // pass1 pairs -> final padded col
    int*  cnt  = (int*)alloc((size_t)NB * P1_BLOCKS * 4);
    int2* row2 = (int2*)alloc((size_t)N_NODES * 8);
    u32*  h0   = (u32*)alloc((size_t)(N_NODES + 1) * HDIM * 2);  // fp16, +sentinel row
    u32*  hA   = (u32*)alloc((size_t)(N_NODES + 1) * HDIM * 2);
    u32*  hB   = (u32*)alloc((size_t)(N_NODES + 1) * HDIM * 2);

    dim3 bL((N_NODES + 31) / 32);   // 3125 blocks x 256 threads (8 lanes/node)

    // ---- CSR build (pass1 also converts x -> fp16 h0) ----
    pass1_bucket<<<P1_BLOCKS, P1_THREADS, 0, stream>>>(src, dst, priv, cnt,
                                                       (const float4*)x, (uint2*)h0);
    pass2_sort<<<NB, 1024, 0, stream>>>(priv, cnt, (int2*)row2);

    // ---- 7 fused layers ----
    sage_layer<16, true, false><<<bL, 256, 0, stream>>>(h0, (const vi2*)row2, priv, Wl1, Wr1, b1, hA);

    u32* cur = hA;
    u32* nxt = hB;
    for (int i = 0; i < 5; ++i) {
        sage_layer<16, true, false><<<bL, 256, 0, stream>>>(
            cur, (const vi2*)row2, priv, Wl_mid + i * 256, Wr_mid + i * 256, b_mid + i * 16, nxt);
        u32* tmp = cur; cur = nxt; nxt = tmp;
    }

    sage_layer<2, false, true><<<bL, 256, 0, stream>>>(cur, (const vi2*)row2, priv, Wl7, Wr7, b7, out);
}

// Round 15
// 190.286 us; speedup vs baseline: 1.7777x; 1.2998x over previous
//
#include <hip/hip_runtime.h>
#include <hip/hip_fp16.h>

#define N_NODES 100000
#define N_EDGES 3200000
#define HDIM 16
#define NB 391                 // buckets of 256 nodes
#define P1_BLOCKS 256
#define P1_THREADS 1024
#define P1_EPB 12500           // 256 * 12500 = 3.2M exactly; 12500 % 4 == 0
#define SLOT 64                // per (bucket, block) private slots: mean 32, sigma 5.7
#define BSTRIDE (P1_BLOCKS * SLOT)   // 16384 u32 per bucket region (also final col region)
#define SENT 0xFBFFFBFFu       // packed fp16 -65504 pair

typedef unsigned u32;

__device__ __forceinline__ u32 pkmax(u32 a, u32 b) {
    u32 r;
    asm("v_pk_max_f16 %0, %1, %2" : "=v"(r) : "v"(a), "v"(b));
    return r;
}
__device__ __forceinline__ float2 h2f2(u32 u) {
    __half2 h = *reinterpret_cast<__half2*>(&u);
    return __half22float2(h);
}
__device__ __forceinline__ u32 f2h2(float a, float b) {
    __half2 h = __float22half2_rn(make_float2(a, b));
    return *reinterpret_cast<u32*>(&h);
}

// ---------------- pass1: single-pass bucket scatter into block-private regions ----------------
// int4-vectorized edge reads (4 edges/iter); folds fp32->fp16 conversion of x + sentinel row.

__global__ __launch_bounds__(P1_THREADS)
void pass1_bucket(const int* __restrict__ src, const int* __restrict__ dst,
                  u32* __restrict__ priv, int* __restrict__ cnt,
                  const float4* __restrict__ x, uint2* __restrict__ h0) {
    __shared__ int lh[NB];
    int t = threadIdx.x;
    int blk = blockIdx.x;

    // folded f2h: 256*1024*2 = 524288 >= 400000 float4s
    {
        int ci = blk * P1_THREADS + t;
        if (ci < N_NODES * HDIM / 4) {
            float4 v = x[ci];
            h0[ci] = make_uint2(f2h2(v.x, v.y), f2h2(v.z, v.w));
        }
        int ci2 = ci + P1_BLOCKS * P1_THREADS;
        if (ci2 < N_NODES * HDIM / 4) {
            float4 v = x[ci2];
            h0[ci2] = make_uint2(f2h2(v.x, v.y), f2h2(v.z, v.w));
        }
        if (blk == 0 && t < 8)
            ((u32*)h0)[(size_t)N_NODES * 8 + t] = SENT;   // sentinel row h0[N]
    }

    for (int i = t; i < NB; i += P1_THREADS) lh[i] = 0;
    __syncthreads();

    int e0 = blk * P1_EPB;
    const int4* d4 = (const int4*)(dst + e0);     // 16B-aligned: (3.2M + blk*12500)*4 % 16 == 0
    const int4* s4 = (const int4*)(src + e0);
    const int n4 = P1_EPB / 4;                    // 3125
    u32* pbase = priv;
    for (int j = t; j < n4; j += P1_THREADS) {
        int4 d = d4[j];
        int4 s = s4[j];
#pragma unroll
        for (int k = 0; k < 4; ++k) {
            int dd = (&d.x)[k];
            int ss = (&s.x)[k];
            int bk = dd >> 8;
            u32 pv = (u32)ss | ((u32)(dd & 255) << 17);
            int r = atomicAdd(&lh[bk], 1);
            if (r < SLOT)                          // statistically never false
                pbase[(size_t)bk * BSTRIDE + blk * SLOT + r] = pv;
        }
    }
    __syncthreads();
    for (int i = t; i < NB; i += P1_THREADS)
        cnt[i * P1_BLOCKS + blk] = min(lh[i], SLOT);
}

// ---------------- pass2: per-bucket counting sort -> row2 + padded col (in-place) ----------------

__global__ __launch_bounds__(1024)
void pass2_sort(u32* __restrict__ priv, const int* __restrict__ cnt,
                int2* __restrict__ row2) {
    __shared__ int sdeg[256], spd[256], ssc[256], scnt[256];
    __shared__ int colst[13312];
    __shared__ int stot;
    int t = threadIdx.x;
    int b = blockIdx.x;
    size_t base = (size_t)b * BSTRIDE;
    int node0 = b << 8;
    int nn = min(256, N_NODES - node0);

    if (t < 256) { sdeg[t] = 0; scnt[t] = cnt[b * P1_BLOCKS + t]; }
    __syncthreads();

    u32 vv[16];
    int rr[16];
#pragma unroll
    for (int k = 0; k < 16; ++k) {                // 16*1024 = 16384 = 256 segs * 64 slots
        int idx = k * 1024 + t;
        int s = idx >> 6, sl = idx & 63;
        rr[k] = -1;
        if (sl < scnt[s]) {
            u32 v = priv[base + idx];             // seg-major: coalesced 256B runs
            vv[k] = v;
            rr[k] = atomicAdd(&sdeg[v >> 17], 1);
        }
    }
    __syncthreads();
    if (t < 256) {
        int d = sdeg[t];
        int pd = (d + 15) & ~15;                  // pad to multiple of 16 (0 stays 0)
        spd[t] = pd;
        ssc[t] = pd;
    }
    __syncthreads();
    for (int off = 1; off < 256; off <<= 1) {
        int u = 0;
        if (t < 256 && t >= off) u = ssc[t - off];
        __syncthreads();
        if (t < 256) ssc[t] += u;
        __syncthreads();
    }
    if (t < 256) {
        int ex = ssc[t] - spd[t];
        ssc[t] = ex;
        if (t < nn) row2[node0 + t] = make_int2((int)base + ex, (int)base + ex + spd[t]);
        if (t == 255) stot = ex + spd[t];
        for (int q = ex + sdeg[t]; q < ex + spd[t]; ++q)
            colst[q] = N_NODES;                   // sentinel pad
    }
    __syncthreads();
#pragma unroll
    for (int k = 0; k < 16; ++k) {
        if (rr[k] >= 0)
            colst[ssc[vv[k] >> 17] + rr[k]] = vv[k] & 0x1FFFF;
    }
    __syncthreads();
    int tot = stot;                               // <= 13056; +48 guards <= 13104 < 16384
    for (int j = t; j < tot; j += 1024) priv[base + j] = (unsigned)colst[j];
    if (t < 48) priv[base + tot + t] = N_NODES;   // prefetch guard sentinels
}

// ---------------- fused SAGE layer: 8 lanes/node, feature-split, 2-deep pipelined gather ----------------

template <int HOUT, bool RELU, bool LSM>
__global__ void sage_layer(const u32* __restrict__ h,       // fp16 rows: 8 u32/node, N+1 rows
                           const int2* __restrict__ row2,
                           const unsigned* __restrict__ col,
                           const float* __restrict__ Wl,
                           const float* __restrict__ Wr,
                           const float* __restrict__ b,
                           void* __restrict__ out) {
    __shared__ float sWl[HDIM * HOUT];
    __shared__ float sWr[HDIM * HOUT];
    __shared__ float sb[HOUT];
    int t = threadIdx.x;
    if (t < HDIM * HOUT) { sWl[t] = Wl[t]; sWr[t] = Wr[t]; }
    if (t < HOUT) sb[t] = b[t];
    if (HOUT == 16) {
        if (blockIdx.x == 0 && t < 8)
            ((u32*)out)[(size_t)N_NODES * 8 + t] = SENT;   // sentinel row for next layer
    }
    // no __syncthreads here — gather loop doesn't touch LDS; sync before matmul

    int nl = t >> 3, g = t & 7, p = g >> 1, hf = g & 1;
    int i = blockIdx.x * 32 + nl;                 // grid covers N exactly (3125*32)

    int2 r2 = row2[i];
    int beg = r2.x, endp = r2.y;
    const uint4* h4 = (const uint4*)h;
    const unsigned* cp = col + 4 * p;

    uint4 xr = h4[i * 2 + hf];

    // prologue: cols for iter0 and iter1, gathers for iter0
    uint4 cc = *(const uint4*)(cp + beg);
    uint4 nc = *(const uint4*)(cp + beg + 16);
    uint4 v0 = h4[(int)cc.x * 2 + hf];
    uint4 v1 = h4[(int)cc.y * 2 + hf];
    uint4 v2 = h4[(int)cc.z * 2 + hf];
    uint4 v3 = h4[(int)cc.w * 2 + hf];

    u32 a0 = SENT, a1 = SENT, a2 = SENT, a3 = SENT;
    for (int j = beg; j < endp; j += 16) {
        // issue iter k+1 gathers and iter k+2 cols (sentinel-guarded)
        uint4 w0 = h4[(int)nc.x * 2 + hf];
        uint4 w1 = h4[(int)nc.y * 2 + hf];
        uint4 w2 = h4[(int)nc.z * 2 + hf];
        uint4 w3 = h4[(int)nc.w * 2 + hf];
        uint4 nc2 = *(const uint4*)(cp + j + 32);
        // consume iter k
        a0 = pkmax(a0, pkmax(pkmax(v0.x, v1.x), pkmax(v2.x, v3.x)));
        a1 = pkmax(a1, pkmax(pkmax(v0.y, v1.y), pkmax(v2.y, v3.y)));
        a2 = pkmax(a2, pkmax(pkmax(v0.z, v1.z), pkmax(v2.z, v3.z)));
        a3 = pkmax(a3, pkmax(pkmax(v0.w, v1.w), pkmax(v2.w, v3.w)));
        v0 = w0; v1 = w1; v2 = w2; v3 = w3;
        nc = nc2;
    }
    // combine the 4 lane-pairs (same half hf)
#pragma unroll
    for (int m = 2; m <= 4; m <<= 1) {
        a0 = pkmax(a0, (u32)__shfl_xor((int)a0, m));
        a1 = pkmax(a1, (u32)__shfl_xor((int)a1, m));
        a2 = pkmax(a2, (u32)__shfl_xor((int)a2, m));
        a3 = pkmax(a3, (u32)__shfl_xor((int)a3, m));
    }
    if (beg == endp) { a0 = a1 = a2 = a3 = 0u; }  // isolated node -> 0

    float fa[8], fx[8];
    {
        float2 f;
        f = h2f2(a0);   fa[0] = f.x; fa[1] = f.y;
        f = h2f2(a1);   fa[2] = f.x; fa[3] = f.y;
        f = h2f2(a2);   fa[4] = f.x; fa[5] = f.y;
        f = h2f2(a3);   fa[6] = f.x; fa[7] = f.y;
        f = h2f2(xr.x); fx[0] = f.x; fx[1] = f.y;
        f = h2f2(xr.y); fx[2] = f.x; fx[3] = f.y;
        f = h2f2(xr.z); fx[4] = f.x; fx[5] = f.y;
        f = h2f2(xr.w); fx[6] = f.x; fx[7] = f.y;
    }
    int fb = hf * 8;

    __syncthreads();                              // weights now needed

    if (HOUT == 16) {
        float o0 = 0.f, o1 = 0.f, o2 = 0.f, o3 = 0.f;
#pragma unroll
        for (int q = 0; q < 8; ++q) {
            int f = fb + q;
            float4 wl = ((const float4*)sWl)[f * 4 + p];
            float4 wr = ((const float4*)sWr)[f * 4 + p];
            o0 += fa[q] * wl.x + fx[q] * wr.x;
            o1 += fa[q] * wl.y + fx[q] * wr.y;
            o2 += fa[q] * wl.z + fx[q] * wr.z;
            o3 += fa[q] * wl.w + fx[q] * wr.w;
        }
        o0 += __shfl_xor(o0, 1);
        o1 += __shfl_xor(o1, 1);
        o2 += __shfl_xor(o2, 1);
        o3 += __shfl_xor(o3, 1);
        if (hf == 0) {
            int c0 = p * 4;
            o0 += sb[c0]; o1 += sb[c0 + 1]; o2 += sb[c0 + 2]; o3 += sb[c0 + 3];
            if (RELU) {
                o0 = fmaxf(o0, 0.f); o1 = fmaxf(o1, 0.f);
                o2 = fmaxf(o2, 0.f); o3 = fmaxf(o3, 0.f);
            }
            ((uint2*)out)[i * 4 + p] = make_uint2(f2h2(o0, o1), f2h2(o2, o3));
        }
    } else {  // HOUT == 2 final layer, fp32 out + log_softmax
        float o0 = 0.f, o1 = 0.f;
#pragma unroll
        for (int q = 0; q < 8; ++q) {
            int f = fb + q;
            o0 += fa[q] * sWl[f * 2 + 0] + fx[q] * sWr[f * 2 + 0];
            o1 += fa[q] * sWl[f * 2 + 1] + fx[q] * sWr[f * 2 + 1];
        }
        o0 += __shfl_xor(o0, 1);
        o1 += __shfl_xor(o1, 1);
        if (g == 0) {
            o0 += sb[0]; o1 += sb[1];
            if (LSM) {
                float m = fmaxf(o0, o1);
                float lse = m + logf(expf(o0 - m) + expf(o1 - m));
                o0 -= lse; o1 -= lse;
            }
            ((float2*)out)[i] = make_float2(o0, o1);
        }
    }
}

// ---------------- launch ----------------

extern "C" void kernel_launch(void* const* d_in, const int* in_sizes, int n_in,
                              void* d_out, int out_size, void* d_ws, size_t ws_size,
                              hipStream_t stream) {
    const float* x      = (const float*)d_in[0];
    const int*   ei     = (const int*)d_in[1];
    const float* Wl1    = (const float*)d_in[2];
    const float* Wr1    = (const float*)d_in[3];
    const float* b1     = (const float*)d_in[4];
    const float* Wl_mid = (const float*)d_in[5];
    const float* Wr_mid = (const float*)d_in[6];
    const float* b_mid  = (const float*)d_in[7];
    const float* Wl7    = (const float*)d_in[8];
    const float* Wr7    = (const float*)d_in[9];
    const float* b7     = (const float*)d_in[10];
    float* out = (float*)d_out;

    const int* src = ei;
    const int* dst = ei + N_EDGES;

    char* ws = (char*)d_ws;
    size_t off = 0;
    auto alloc = [&](size_t bytes) {
        void* p = ws + off;
        off += (bytes + 255) & ~(size_t)255;
        return p;
    };
    u32*  priv = (u32*)alloc((size_t)NB * BSTRIDE * 4);   // pass1 pairs -> final padded col
    int*  cnt  = (int*)alloc((size_t)NB * P1_BLOCKS * 4);
    int2* row2 = (int2*)alloc((size_t)N_NODES * 8);
    u32*  h0   = (u32*)alloc((size_t)(N_NODES + 1) * HDIM * 2);  // fp16, +sentinel row
    u32*  hA   = (u32*)alloc((size_t)(N_NODES + 1) * HDIM * 2);
    u32*  hB   = (u32*)alloc((size_t)(N_NODES + 1) * HDIM * 2);

    dim3 bL((N_NODES + 31) / 32);   // 3125 blocks x 256 threads (8 lanes/node)

    // ---- CSR build (pass1 also converts x -> fp16 h0) ----
    pass1_bucket<<<P1_BLOCKS, P1_THREADS, 0, stream>>>(src, dst, priv, cnt,
                                                       (const float4*)x, (uint2*)h0);
    pass2_sort<<<NB, 1024, 0, stream>>>(priv, cnt, row2);

    // ---- 7 fused layers ----
    sage_layer<16, true, false><<<bL, 256, 0, stream>>>(h0, row2, priv, Wl1, Wr1, b1, hA);

    u32* cur = hA;
    u32* nxt = hB;
    for (int i = 0; i < 5; ++i) {
        sage_layer<16, true, false><<<bL, 256, 0, stream>>>(
            cur, row2, priv, Wl_mid + i * 256, Wr_mid + i * 256, b_mid + i * 16, nxt);
        u32* tmp = cur; cur = nxt; nxt = tmp;
    }

    sage_layer<2, false, true><<<bL, 256, 0, stream>>>(cur, row2, priv, Wl7, Wr7, b7, out);
}

// Round 16
// 188.770 us; speedup vs baseline: 1.7920x; 1.0080x over previous
//
#include <hip/hip_runtime.h>
#include <hip/hip_fp16.h>

#define N_NODES 100000
#define N_EDGES 3200000
#define HDIM 16
#define NB 391                 // buckets of 256 nodes
#define P1_BLOCKS 256
#define P1_THREADS 1024
#define P1_EPB 12500           // 256 * 12500 = 3.2M exactly
#define P1_HALF 6250           // two staging halves per block
#define SLOT 64                // per (bucket, block) private slots: mean 32, sigma 5.7
#define BSTRIDE (P1_BLOCKS * SLOT)   // 16384 u32 per bucket region (also final col region)
#define SENT 0xFBFFFBFFu       // packed fp16 -65504 pair

typedef unsigned u32;

__device__ __forceinline__ u32 pkmax(u32 a, u32 b) {
    u32 r;
    asm("v_pk_max_f16 %0, %1, %2" : "=v"(r) : "v"(a), "v"(b));
    return r;
}
__device__ __forceinline__ float2 h2f2(u32 u) {
    __half2 h = *reinterpret_cast<__half2*>(&u);
    return __half22float2(h);
}
__device__ __forceinline__ u32 f2h2(float a, float b) {
    __half2 h = __float22half2_rn(make_float2(a, b));
    return *reinterpret_cast<u32*>(&h);
}

// ---------------- pass1: bucket partition with LDS write-combining ----------------
// Per half: count+rank (LDS atomics) -> scan 8-padded counts -> scatter into staged
// LDS -> COALESCED copy-out of contiguous bucket runs. Kills the 64-distinct-line
// scattered stores that pinned pass1 at 40us (r7/r9 both scatter-bound at 40).
// Also folds fp32->fp16 conversion of x + sentinel row.

__global__ __launch_bounds__(P1_THREADS)
void pass1_bucket(const int* __restrict__ src, const int* __restrict__ dst,
                  u32* __restrict__ priv, int* __restrict__ cnt,
                  const float4* __restrict__ x, uint2* __restrict__ h0) {
    __shared__ int lh[NB];                 // per-half bucket counts
    __shared__ int cum[NB];                // cumulative counts across halves
    __shared__ int pexcl[512];             // inclusive scan of 8-padded counts
    __shared__ unsigned short c2b[1152];   // staged-chunk (8 u32) -> bucket
    __shared__ u32 staged[8992];           // 6250 + 391*7 max
    int t = threadIdx.x;
    int blk = blockIdx.x;

    // folded f2h: 256*1024*2 = 524288 >= 400000 float4s
    {
        int ci = blk * P1_THREADS + t;
        if (ci < N_NODES * HDIM / 4) {
            float4 v = x[ci];
            h0[ci] = make_uint2(f2h2(v.x, v.y), f2h2(v.z, v.w));
        }
        int ci2 = ci + P1_BLOCKS * P1_THREADS;
        if (ci2 < N_NODES * HDIM / 4) {
            float4 v = x[ci2];
            h0[ci2] = make_uint2(f2h2(v.x, v.y), f2h2(v.z, v.w));
        }
        if (blk == 0 && t < 8)
            ((u32*)h0)[(size_t)N_NODES * 8 + t] = SENT;   // sentinel row h0[N]
    }

    for (int i = t; i < NB; i += P1_THREADS) cum[i] = 0;

    for (int half = 0; half < 2; ++half) {
        for (int i = t; i < NB; i += P1_THREADS) lh[i] = 0;
        __syncthreads();

        int e0 = blk * P1_EPB + half * P1_HALF;
        u32 vv[7];
        int br[7];                                   // (rank<<9)|bucket, -1 = none
#pragma unroll
        for (int k = 0; k < 7; ++k) {
            int j = k * P1_THREADS + t;
            br[k] = -1;
            if (j < P1_HALF) {
                int d = dst[e0 + j];
                int s = src[e0 + j];
                int bk = d >> 8;
                vv[k] = (u32)s | ((u32)(d & 255) << 17);
                int r = atomicAdd(&lh[bk], 1);
                br[k] = (r << 9) | bk;
            }
        }
        __syncthreads();

        // inclusive scan of 8-padded counts over 512 slots
        int pc = 0;
        if (t < 512) {
            pc = (t < NB) ? ((lh[t] + 7) & ~7) : 0;
            pexcl[t] = pc;
        }
        __syncthreads();
        for (int off = 1; off < 512; off <<= 1) {
            int u = 0;
            if (t < 512 && t >= off) u = pexcl[t - off];
            __syncthreads();
            if (t < 512) pexcl[t] += u;
            __syncthreads();
        }
        // chunk->bucket map (runs are 8-aligned in staged space)
        if (t < NB) {
            int ex = pexcl[t] - pc;
            for (int c = ex >> 3; c < (pexcl[t] >> 3); ++c)
                c2b[c] = (unsigned short)t;
        }
        // scatter into staged LDS (in-bounds by construction: r < lh[bk] <= pad)
#pragma unroll
        for (int k = 0; k < 7; ++k) {
            if (br[k] >= 0) {
                int bk = br[k] & 511;
                int r = br[k] >> 9;
                int ex = pexcl[bk] - ((lh[bk] + 7) & ~7);
                staged[ex + r] = vv[k];
            }
        }
        __syncthreads();

        // coalesced copy-out: consecutive threads -> consecutive run elements
        int tot = pexcl[511];
        for (int j = t; j < tot; j += P1_THREADS) {
            int bk = c2b[j >> 3];
            int ex = pexcl[bk] - ((lh[bk] + 7) & ~7);
            int off2 = j - ex;
            int base = cum[bk];
            if (off2 < lh[bk] && base + off2 < SLOT)  // skip pad; clip (stat. never)
                priv[(size_t)bk * BSTRIDE + blk * SLOT + base + off2] = staged[j];
        }
        __syncthreads();
        for (int i = t; i < NB; i += P1_THREADS) cum[i] += lh[i];
        __syncthreads();
    }

    for (int i = t; i < NB; i += P1_THREADS)
        cnt[i * P1_BLOCKS + blk] = min(cum[i], SLOT);
}

// ---------------- pass2: per-bucket counting sort -> row2 + padded col (in-place) ----------------

__global__ __launch_bounds__(1024)
void pass2_sort(u32* __restrict__ priv, const int* __restrict__ cnt,
                int2* __restrict__ row2) {
    __shared__ int sdeg[256], spd[256], ssc[256], scnt[256];
    __shared__ int colst[13312];
    __shared__ int stot;
    int t = threadIdx.x;
    int b = blockIdx.x;
    size_t base = (size_t)b * BSTRIDE;
    int node0 = b << 8;
    int nn = min(256, N_NODES - node0);

    if (t < 256) { sdeg[t] = 0; scnt[t] = cnt[b * P1_BLOCKS + t]; }
    __syncthreads();

    u32 vv[16];
    int rr[16];
#pragma unroll
    for (int k = 0; k < 16; ++k) {                // 16*1024 = 16384 = 256 segs * 64 slots
        int idx = k * 1024 + t;
        int s = idx >> 6, sl = idx & 63;
        rr[k] = -1;
        if (sl < scnt[s]) {
            u32 v = priv[base + idx];             // seg-major: coalesced 256B runs
            vv[k] = v;
            rr[k] = atomicAdd(&sdeg[v >> 17], 1);
        }
    }
    __syncthreads();
    if (t < 256) {
        int d = sdeg[t];
        int pd = (d + 15) & ~15;                  // pad to multiple of 16 (0 stays 0)
        spd[t] = pd;
        ssc[t] = pd;
    }
    __syncthreads();
    for (int off = 1; off < 256; off <<= 1) {
        int u = 0;
        if (t < 256 && t >= off) u = ssc[t - off];
        __syncthreads();
        if (t < 256) ssc[t] += u;
        __syncthreads();
    }
    if (t < 256) {
        int ex = ssc[t] - spd[t];
        ssc[t] = ex;
        if (t < nn) row2[node0 + t] = make_int2((int)base + ex, (int)base + ex + spd[t]);
        if (t == 255) stot = ex + spd[t];
        for (int q = ex + sdeg[t]; q < ex + spd[t]; ++q)
            colst[q] = N_NODES;                   // sentinel pad
    }
    __syncthreads();
#pragma unroll
    for (int k = 0; k < 16; ++k) {
        if (rr[k] >= 0)
            colst[ssc[vv[k] >> 17] + rr[k]] = vv[k] & 0x1FFFF;
    }
    __syncthreads();
    int tot = stot;                               // <= 13056; +48 guards <= 13104 < 16384
    for (int j = t; j < tot; j += 1024) priv[base + j] = (unsigned)colst[j];
    if (t < 48) priv[base + tot + t] = N_NODES;   // prefetch guard sentinels
}

// ---------------- fused SAGE layer: 8 lanes/node, feature-split, 2-deep pipelined gather ----------------

template <int HOUT, bool RELU, bool LSM>
__global__ void sage_layer(const u32* __restrict__ h,       // fp16 rows: 8 u32/node, N+1 rows
                           const int2* __restrict__ row2,
                           const unsigned* __restrict__ col,
                           const float* __restrict__ Wl,
                           const float* __restrict__ Wr,
                           const float* __restrict__ b,
                           void* __restrict__ out) {
    __shared__ float sWl[HDIM * HOUT];
    __shared__ float sWr[HDIM * HOUT];
    __shared__ float sb[HOUT];
    int t = threadIdx.x;
    if (t < HDIM * HOUT) { sWl[t] = Wl[t]; sWr[t] = Wr[t]; }
    if (t < HOUT) sb[t] = b[t];
    if (HOUT == 16) {
        if (blockIdx.x == 0 && t < 8)
            ((u32*)out)[(size_t)N_NODES * 8 + t] = SENT;   // sentinel row for next layer
    }
    // no __syncthreads here — gather loop doesn't touch LDS; sync before matmul

    int nl = t >> 3, g = t & 7, p = g >> 1, hf = g & 1;
    int i = blockIdx.x * 32 + nl;                 // grid covers N exactly (3125*32)

    int2 r2 = row2[i];
    int beg = r2.x, endp = r2.y;
    const uint4* h4 = (const uint4*)h;
    const unsigned* cp = col + 4 * p;

    uint4 xr = h4[i * 2 + hf];

    // prologue: cols for iter0 and iter1, gathers for iter0
    uint4 cc = *(const uint4*)(cp + beg);
    uint4 nc = *(const uint4*)(cp + beg + 16);
    uint4 v0 = h4[(int)cc.x * 2 + hf];
    uint4 v1 = h4[(int)cc.y * 2 + hf];
    uint4 v2 = h4[(int)cc.z * 2 + hf];
    uint4 v3 = h4[(int)cc.w * 2 + hf];

    u32 a0 = SENT, a1 = SENT, a2 = SENT, a3 = SENT;
    for (int j = beg; j < endp; j += 16) {
        // issue iter k+1 gathers and iter k+2 cols (sentinel-guarded)
        uint4 w0 = h4[(int)nc.x * 2 + hf];
        uint4 w1 = h4[(int)nc.y * 2 + hf];
        uint4 w2 = h4[(int)nc.z * 2 + hf];
        uint4 w3 = h4[(int)nc.w * 2 + hf];
        uint4 nc2 = *(const uint4*)(cp + j + 32);
        // consume iter k
        a0 = pkmax(a0, pkmax(pkmax(v0.x, v1.x), pkmax(v2.x, v3.x)));
        a1 = pkmax(a1, pkmax(pkmax(v0.y, v1.y), pkmax(v2.y, v3.y)));
        a2 = pkmax(a2, pkmax(pkmax(v0.z, v1.z), pkmax(v2.z, v3.z)));
        a3 = pkmax(a3, pkmax(pkmax(v0.w, v1.w), pkmax(v2.w, v3.w)));
        v0 = w0; v1 = w1; v2 = w2; v3 = w3;
        nc = nc2;
    }
    // combine the 4 lane-pairs (same half hf)
#pragma unroll
    for (int m = 2; m <= 4; m <<= 1) {
        a0 = pkmax(a0, (u32)__shfl_xor((int)a0, m));
        a1 = pkmax(a1, (u32)__shfl_xor((int)a1, m));
        a2 = pkmax(a2, (u32)__shfl_xor((int)a2, m));
        a3 = pkmax(a3, (u32)__shfl_xor((int)a3, m));
    }
    if (beg == endp) { a0 = a1 = a2 = a3 = 0u; }  // isolated node -> 0

    float fa[8], fx[8];
    {
        float2 f;
        f = h2f2(a0);   fa[0] = f.x; fa[1] = f.y;
        f = h2f2(a1);   fa[2] = f.x; fa[3] = f.y;
        f = h2f2(a2);   fa[4] = f.x; fa[5] = f.y;
        f = h2f2(a3);   fa[6] = f.x; fa[7] = f.y;
        f = h2f2(xr.x); fx[0] = f.x; fx[1] = f.y;
        f = h2f2(xr.y); fx[2] = f.x; fx[3] = f.y;
        f = h2f2(xr.z); fx[4] = f.x; fx[5] = f.y;
        f = h2f2(xr.w); fx[6] = f.x; fx[7] = f.y;
    }
    int fb = hf * 8;

    __syncthreads();                              // weights now needed

    if (HOUT == 16) {
        float o0 = 0.f, o1 = 0.f, o2 = 0.f, o3 = 0.f;
#pragma unroll
        for (int q = 0; q < 8; ++q) {
            int f = fb + q;
            float4 wl = ((const float4*)sWl)[f * 4 + p];
            float4 wr = ((const float4*)sWr)[f * 4 + p];
            o0 += fa[q] * wl.x + fx[q] * wr.x;
            o1 += fa[q] * wl.y + fx[q] * wr.y;
            o2 += fa[q] * wl.z + fx[q] * wr.z;
            o3 += fa[q] * wl.w + fx[q] * wr.w;
        }
        o0 += __shfl_xor(o0, 1);
        o1 += __shfl_xor(o1, 1);
        o2 += __shfl_xor(o2, 1);
        o3 += __shfl_xor(o3, 1);
        if (hf == 0) {
            int c0 = p * 4;
            o0 += sb[c0]; o1 += sb[c0 + 1]; o2 += sb[c0 + 2]; o3 += sb[c0 + 3];
            if (RELU) {
                o0 = fmaxf(o0, 0.f); o1 = fmaxf(o1, 0.f);
                o2 = fmaxf(o2, 0.f); o3 = fmaxf(o3, 0.f);
            }
            ((uint2*)out)[i * 4 + p] = make_uint2(f2h2(o0, o1), f2h2(o2, o3));
        }
    } else {  // HOUT == 2 final layer, fp32 out + log_softmax
        float o0 = 0.f, o1 = 0.f;
#pragma unroll
        for (int q = 0; q < 8; ++q) {
            int f = fb + q;
            o0 += fa[q] * sWl[f * 2 + 0] + fx[q] * sWr[f * 2 + 0];
            o1 += fa[q] * sWl[f * 2 + 1] + fx[q] * sWr[f * 2 + 1];
        }
        o0 += __shfl_xor(o0, 1);
        o1 += __shfl_xor(o1, 1);
        if (g == 0) {
            o0 += sb[0]; o1 += sb[1];
            if (LSM) {
                float m = fmaxf(o0, o1);
                float lse = m + logf(expf(o0 - m) + expf(o1 - m));
                o0 -= lse; o1 -= lse;
            }
            ((float2*)out)[i] = make_float2(o0, o1);
        }
    }
}

// ---------------- launch ----------------

extern "C" void kernel_launch(void* const* d_in, const int* in_sizes, int n_in,
                              void* d_out, int out_size, void* d_ws, size_t ws_size,
                              hipStream_t stream) {
    const float* x      = (const float*)d_in[0];
    const int*   ei     = (const int*)d_in[1];
    const float* Wl1    = (const float*)d_in[2];
    const float* Wr1    = (const float*)d_in[3];
    const float* b1     = (const float*)d_in[4];
    const float* Wl_mid = (const float*)d_in[5];
    const float* Wr_mid = (const float*)d_in[6];
    const float* b_mid  = (const float*)d_in[7];
    const float* Wl7    = (const float*)d_in[8];
    const float* Wr7    = (const float*)d_in[9];
    const float* b7     = (const float*)d_in[10];
    float* out = (float*)d_out;

    const int* src = ei;
    const int* dst = ei + N_EDGES;

    char* ws = (char*)d_ws;
    size_t off = 0;
    auto alloc = [&](size_t bytes) {
        void* p = ws + off;
        off += (bytes + 255) & ~(size_t)255;
        return p;
    };
    u32*  priv = (u32*)alloc((size_t)NB * BSTRIDE * 4);   // pass1 pairs -> final padded col
    int*  cnt  = (int*)alloc((size_t)NB * P1_BLOCKS * 4);
    int2* row2 = (int2*)alloc((size_t)N_NODES * 8);
    u32*  h0   = (u32*)alloc((size_t)(N_NODES + 1) * HDIM * 2);  // fp16, +sentinel row
    u32*  hA   = (u32*)alloc((size_t)(N_NODES + 1) * HDIM * 2);
    u32*  hB   = (u32*)alloc((size_t)(N_NODES + 1) * HDIM * 2);

    dim3 bL((N_NODES + 31) / 32);   // 3125 blocks x 256 threads (8 lanes/node)

    // ---- CSR build (pass1 also converts x -> fp16 h0) ----
    pass1_bucket<<<P1_BLOCKS, P1_THREADS, 0, stream>>>(src, dst, priv, cnt,
                                                       (const float4*)x, (uint2*)h0);
    pass2_sort<<<NB, 1024, 0, stream>>>(priv, cnt, row2);

    // ---- 7 fused layers ----
    sage_layer<16, true, false><<<bL, 256, 0, stream>>>(h0, row2, priv, Wl1, Wr1, b1, hA);

    u32* cur = hA;
    u32* nxt = hB;
    for (int i = 0; i < 5; ++i) {
        sage_layer<16, true, false><<<bL, 256, 0, stream>>>(
            cur, row2, priv, Wl_mid + i * 256, Wr_mid + i * 256, b_mid + i * 16, nxt);
        u32* tmp = cur; cur = nxt; nxt = tmp;
    }

    sage_layer<2, false, true><<<bL, 256, 0, stream>>>(cur, row2, priv, Wl7, Wr7, b7, out);
}